// Round 13
// baseline (368.907 us; speedup 1.0000x reference)
//
#include <hip/hip_runtime.h>
#include <math.h>

#define HH 64

// ---------------- init ----------------

__global__ void k_init(int* __restrict__ head, float* __restrict__ sums,
                       int* __restrict__ cursor, int n, int pn) {
    int i = blockIdx.x * blockDim.x + threadIdx.x;
    if (i < n) head[i] = -1;
    if (i < pn) sums[i] = 0.f;
    if (i == 0) *cursor = 0;
}

// ---------------- CSR build: pure linked-list pass (the atomic-scatter floor) ----------------
__global__ void k_link(const int* __restrict__ col, int E,
                       int* __restrict__ head, int* __restrict__ next) {
    int e = blockIdx.x * blockDim.x + threadIdx.x;
    if (e >= E) return;
    int c = col[e];
    int prev = atomicExch(&head[c], e);
    next[e] = prev;
}

// ---------------- fused: list-walk/CSR-alloc + layer-1 GEMM ----------------
// Walk is dependent-load latency-bound (~0% VALU); the FIN=128 GEMM hides
// under it. GEMM output UNSCALED (layer-1 gather applies dinv[src] per edge).
template<int FIN>
__global__ __launch_bounds__(256, 3) void k_walk_gemm(const int* __restrict__ row,
                                                      const int* __restrict__ head,
                                                      const int* __restrict__ next,
                                                      int* __restrict__ cursor,
                                                      int* __restrict__ rowptr,
                                                      int* __restrict__ cnt,
                                                      float* __restrict__ dinv,
                                                      int* __restrict__ csr,
                                                      const float* __restrict__ x,
                                                      const float* __restrict__ W,
                                                      float* __restrict__ lin, int n) {
    constexpr int KC = 32;
    constexpr int XS = 68;
    __shared__ __align__(16) float Ws[FIN][HH];
    __shared__ __align__(16) float xs_t[KC][XS];
    const int tid = threadIdx.x;

    // ---- walk + alloc (first 196 blocks cover N at 256 nodes/block) ----
    {
        int node = blockIdx.x * 256 + tid;
        int lane = tid & 63;
        if (node - tid < n) {                     // block participates
            int len = 0, h = -1;
            if (node < n) {
                h = head[node];
                for (int p = h; p >= 0; p = next[p]) ++len;
                dinv[node] = rsqrtf((float)(len + 1));
            }
            int incl = len;
#pragma unroll
            for (int off = 1; off < 64; off <<= 1) {
                int t = __shfl_up(incl, off, 64);
                if (lane >= off) incl += t;
            }
            int total = __shfl(incl, 63, 64);
            int base = 0;
            if (lane == 0 && total > 0) base = atomicAdd(cursor, total);
            base = __shfl(base, 0, 64);
            int dst = base + incl - len;
            if (node < n) {
                rowptr[node] = dst;
                cnt[node]    = len;
                for (int p = h; p >= 0; p = next[p]) csr[dst++] = row[p];
            }
        }
    }

    // ---- layer-1 gemm (64 nodes per block) ----
    const int tx = tid & 15;
    const int ty = tid >> 4;
    const int node0 = blockIdx.x * 64;
    if (node0 >= n) return;

    for (int i = tid * 4; i < FIN * HH; i += 1024)
        *(float4*)&Ws[0][i] = *(const float4*)&W[i];

    float acc[4][4] = {};
    const int rr0 = tid >> 3;
    const int cc  = (tid & 7) * 4;

    for (int kc = 0; kc < FIN; kc += KC) {
        __syncthreads();
        for (int rr = rr0; rr < 64; rr += 32) {
            float4 v = make_float4(0.f, 0.f, 0.f, 0.f);
            if (node0 + rr < n) v = *(const float4*)&x[(size_t)(node0 + rr) * FIN + kc + cc];
            xs_t[cc + 0][rr] = v.x;
            xs_t[cc + 1][rr] = v.y;
            xs_t[cc + 2][rr] = v.z;
            xs_t[cc + 3][rr] = v.w;
        }
        __syncthreads();
#pragma unroll 4
        for (int k = 0; k < KC; ++k) {
            float4 a4 = *(const float4*)&xs_t[k][ty * 4];
            float4 b4 = *(const float4*)&Ws[kc + k][tx * 4];
            acc[0][0] = fmaf(a4.x, b4.x, acc[0][0]);
            acc[0][1] = fmaf(a4.x, b4.y, acc[0][1]);
            acc[0][2] = fmaf(a4.x, b4.z, acc[0][2]);
            acc[0][3] = fmaf(a4.x, b4.w, acc[0][3]);
            acc[1][0] = fmaf(a4.y, b4.x, acc[1][0]);
            acc[1][1] = fmaf(a4.y, b4.y, acc[1][1]);
            acc[1][2] = fmaf(a4.y, b4.z, acc[1][2]);
            acc[1][3] = fmaf(a4.y, b4.w, acc[1][3]);
            acc[2][0] = fmaf(a4.z, b4.x, acc[2][0]);
            acc[2][1] = fmaf(a4.z, b4.y, acc[2][1]);
            acc[2][2] = fmaf(a4.z, b4.z, acc[2][2]);
            acc[2][3] = fmaf(a4.z, b4.w, acc[2][3]);
            acc[3][0] = fmaf(a4.w, b4.x, acc[3][0]);
            acc[3][1] = fmaf(a4.w, b4.y, acc[3][1]);
            acc[3][2] = fmaf(a4.w, b4.z, acc[3][2]);
            acc[3][3] = fmaf(a4.w, b4.w, acc[3][3]);
        }
    }

#pragma unroll
    for (int i = 0; i < 4; ++i) {
        int node = node0 + ty * 4 + i;
        if (node < n) *(float4*)&lin[(size_t)node * HH + tx * 4] = *(float4*)acc[i];
    }
}

// ---------------- fused gather + next-layer GEMM ----------------
// After computing this node's h-row (lane=feature), immediately compute
// linS_next[node][lane] = dinv[node] * sum_k h[k]*Wn[k][lane] via shfl
// broadcast + LDS-staged Wn. Intermediate h never touches memory.
// WEIGHTED variant (layer 1): lin unscaled, per-edge weight dinv[src].
__global__ __launch_bounds__(256) void k_gather_w_gemm(const float* __restrict__ lin,
                                                       const int* __restrict__ csr,
                                                       const int* __restrict__ rowptr,
                                                       const int* __restrict__ cnt,
                                                       const float* __restrict__ dinv,
                                                       const float* __restrict__ b,
                                                       const float* __restrict__ Wn,
                                                       float* __restrict__ linS_out, int n) {
    __shared__ __align__(16) float Wls[HH][HH];
    const int tid = threadIdx.x;
    for (int i = tid * 4; i < HH * HH; i += 1024)
        *(float4*)&Wls[0][i] = *(const float4*)&Wn[i];
    __syncthreads();

    int node = blockIdx.x * 4 + (tid >> 6);
    int lane = tid & 63;
    if (node >= n) return;
    int start = rowptr[node];
    int end = start + cnt[node];
    float di = dinv[node];
    float acc0 = di * lin[(size_t)node * HH + lane];
    float acc1 = 0.f, acc2 = 0.f, acc3 = 0.f;
    for (int base = start; base < end; base += 64) {
        int m = end - base; if (m > 64) m = 64;
        int   sv = (base + lane < end) ? csr[base + lane] : 0;
        float wv = (base + lane < end) ? dinv[sv] : 0.f;
        int j = 0;
        for (; j + 3 < m; j += 4) {
            int s0 = __shfl(sv, j, 64);     float w0 = __shfl(wv, j, 64);
            int s1 = __shfl(sv, j + 1, 64); float w1 = __shfl(wv, j + 1, 64);
            int s2 = __shfl(sv, j + 2, 64); float w2 = __shfl(wv, j + 2, 64);
            int s3 = __shfl(sv, j + 3, 64); float w3 = __shfl(wv, j + 3, 64);
            float v0 = lin[(size_t)s0 * HH + lane];
            float v1 = lin[(size_t)s1 * HH + lane];
            float v2 = lin[(size_t)s2 * HH + lane];
            float v3 = lin[(size_t)s3 * HH + lane];
            acc0 = fmaf(w0, v0, acc0);
            acc1 = fmaf(w1, v1, acc1);
            acc2 = fmaf(w2, v2, acc2);
            acc3 = fmaf(w3, v3, acc3);
        }
        for (; j < m; ++j) {
            int s0 = __shfl(sv, j, 64); float w0 = __shfl(wv, j, 64);
            acc0 = fmaf(w0, lin[(size_t)s0 * HH + lane], acc0);
        }
    }
    float v = di * ((acc0 + acc1) + (acc2 + acc3)) + b[lane];
    float ss = v * v;
#pragma unroll
    for (int off = 1; off < 64; off <<= 1) ss += __shfl_xor(ss, off, 64);
    v = v / fmaxf(sqrtf(ss), 1e-12f);
    v = fmaxf(v, 0.f);                       // h for this node, lane=feature

    // fused next-layer gemm: 4 independent fma chains
    float g0 = 0.f, g1 = 0.f, g2 = 0.f, g3 = 0.f;
#pragma unroll
    for (int k = 0; k < HH; k += 4) {
        float h0 = __shfl(v, k, 64);
        float h1 = __shfl(v, k + 1, 64);
        float h2 = __shfl(v, k + 2, 64);
        float h3 = __shfl(v, k + 3, 64);
        g0 = fmaf(h0, Wls[k][lane], g0);
        g1 = fmaf(h1, Wls[k + 1][lane], g1);
        g2 = fmaf(h2, Wls[k + 2][lane], g2);
        g3 = fmaf(h3, Wls[k + 3][lane], g3);
    }
    linS_out[(size_t)node * HH + lane] = di * ((g0 + g1) + (g2 + g3));
}

// PRE-SCALED variant (layer 2): linS input, fused layer-3 gemm.
__global__ __launch_bounds__(256) void k_gather_gemm(const float* __restrict__ linS,
                                                     const int* __restrict__ csr,
                                                     const int* __restrict__ rowptr,
                                                     const int* __restrict__ cnt,
                                                     const float* __restrict__ dinv,
                                                     const float* __restrict__ b,
                                                     const float* __restrict__ Wn,
                                                     float* __restrict__ linS_out, int n) {
    __shared__ __align__(16) float Wls[HH][HH];
    const int tid = threadIdx.x;
    for (int i = tid * 4; i < HH * HH; i += 1024)
        *(float4*)&Wls[0][i] = *(const float4*)&Wn[i];
    __syncthreads();

    int node = blockIdx.x * 4 + (tid >> 6);
    int lane = tid & 63;
    if (node >= n) return;
    int start = rowptr[node];
    int end = start + cnt[node];
    float di = dinv[node];
    float acc0 = linS[(size_t)node * HH + lane];
    float acc1 = 0.f, acc2 = 0.f, acc3 = 0.f;
    for (int base = start; base < end; base += 64) {
        int m = end - base; if (m > 64) m = 64;
        int sv = (base + lane < end) ? csr[base + lane] : 0;
        int j = 0;
        for (; j + 7 < m; j += 8) {
            int s0 = __shfl(sv, j, 64);
            int s1 = __shfl(sv, j + 1, 64);
            int s2 = __shfl(sv, j + 2, 64);
            int s3 = __shfl(sv, j + 3, 64);
            int s4 = __shfl(sv, j + 4, 64);
            int s5 = __shfl(sv, j + 5, 64);
            int s6 = __shfl(sv, j + 6, 64);
            int s7 = __shfl(sv, j + 7, 64);
            float v0 = linS[(size_t)s0 * HH + lane];
            float v1 = linS[(size_t)s1 * HH + lane];
            float v2 = linS[(size_t)s2 * HH + lane];
            float v3 = linS[(size_t)s3 * HH + lane];
            float v4 = linS[(size_t)s4 * HH + lane];
            float v5 = linS[(size_t)s5 * HH + lane];
            float v6 = linS[(size_t)s6 * HH + lane];
            float v7 = linS[(size_t)s7 * HH + lane];
            acc0 += v0; acc1 += v1; acc2 += v2; acc3 += v3;
            acc0 += v4; acc1 += v5; acc2 += v6; acc3 += v7;
        }
        for (; j < m; ++j) {
            int s0 = __shfl(sv, j, 64);
            acc0 += linS[(size_t)s0 * HH + lane];
        }
    }
    float v = di * ((acc0 + acc1) + (acc2 + acc3)) + b[lane];
    float ss = v * v;
#pragma unroll
    for (int off = 1; off < 64; off <<= 1) ss += __shfl_xor(ss, off, 64);
    v = v / fmaxf(sqrtf(ss), 1e-12f);
    v = fmaxf(v, 0.f);

    float g0 = 0.f, g1 = 0.f, g2 = 0.f, g3 = 0.f;
#pragma unroll
    for (int k = 0; k < HH; k += 4) {
        float h0 = __shfl(v, k, 64);
        float h1 = __shfl(v, k + 1, 64);
        float h2 = __shfl(v, k + 2, 64);
        float h3 = __shfl(v, k + 3, 64);
        g0 = fmaf(h0, Wls[k][lane], g0);
        g1 = fmaf(h1, Wls[k + 1][lane], g1);
        g2 = fmaf(h2, Wls[k + 2][lane], g2);
        g3 = fmaf(h3, Wls[k + 3][lane], g3);
    }
    linS_out[(size_t)node * HH + lane] = di * ((g0 + g1) + (g2 + g3));
}

// FINAL layer gather: linS input, writes node_emb (plain h).
__global__ __launch_bounds__(256) void k_gather_final(const float* __restrict__ linS,
                                                      const int* __restrict__ csr,
                                                      const int* __restrict__ rowptr,
                                                      const int* __restrict__ cnt,
                                                      const float* __restrict__ dinv,
                                                      const float* __restrict__ b,
                                                      float* __restrict__ hout, int n) {
    int node = blockIdx.x * 4 + (threadIdx.x >> 6);
    int lane = threadIdx.x & 63;
    if (node >= n) return;
    int start = rowptr[node];
    int end = start + cnt[node];
    float di = dinv[node];
    float acc0 = linS[(size_t)node * HH + lane];
    float acc1 = 0.f, acc2 = 0.f, acc3 = 0.f;
    for (int base = start; base < end; base += 64) {
        int m = end - base; if (m > 64) m = 64;
        int sv = (base + lane < end) ? csr[base + lane] : 0;
        int j = 0;
        for (; j + 7 < m; j += 8) {
            int s0 = __shfl(sv, j, 64);
            int s1 = __shfl(sv, j + 1, 64);
            int s2 = __shfl(sv, j + 2, 64);
            int s3 = __shfl(sv, j + 3, 64);
            int s4 = __shfl(sv, j + 4, 64);
            int s5 = __shfl(sv, j + 5, 64);
            int s6 = __shfl(sv, j + 6, 64);
            int s7 = __shfl(sv, j + 7, 64);
            float v0 = linS[(size_t)s0 * HH + lane];
            float v1 = linS[(size_t)s1 * HH + lane];
            float v2 = linS[(size_t)s2 * HH + lane];
            float v3 = linS[(size_t)s3 * HH + lane];
            float v4 = linS[(size_t)s4 * HH + lane];
            float v5 = linS[(size_t)s5 * HH + lane];
            float v6 = linS[(size_t)s6 * HH + lane];
            float v7 = linS[(size_t)s7 * HH + lane];
            acc0 += v0; acc1 += v1; acc2 += v2; acc3 += v3;
            acc0 += v4; acc1 += v5; acc2 += v6; acc3 += v7;
        }
        for (; j < m; ++j) {
            int s0 = __shfl(sv, j, 64);
            acc0 += linS[(size_t)s0 * HH + lane];
        }
    }
    float v = di * ((acc0 + acc1) + (acc2 + acc3)) + b[lane];
    float ss = v * v;
#pragma unroll
    for (int off = 1; off < 64; off <<= 1) ss += __shfl_xor(ss, off, 64);
    v = v / fmaxf(sqrtf(ss), 1e-12f);
    hout[(size_t)node * HH + lane] = fmaxf(v, 0.f);
}

// ---------------- pooling ----------------
__global__ __launch_bounds__(256) void k_pool(const float* __restrict__ node_emb,
                                              const int* __restrict__ batch,
                                              float* __restrict__ sums,
                                              float* __restrict__ cnts, int n) {
    const int NPW = 16;
    int wave = blockIdx.x * 4 + (threadIdx.x >> 6);
    int lane = threadIdx.x & 63;
    int start = wave * NPW;
    if (start >= n) return;
    int end = start + NPW; if (end > n) end = n;
    int cur = batch[start];
    float acc = 0.f;
    int runlen = 0;
    for (int node = start; node < end; ++node) {
        int g = batch[node];
        if (g != cur) {
            atomicAdd(&sums[(size_t)cur * HH + lane], acc);
            if (lane == 0) atomicAdd(&cnts[cur], (float)runlen);
            acc = 0.f; runlen = 0; cur = g;
        }
        acc += node_emb[(size_t)node * HH + lane];
        ++runlen;
    }
    atomicAdd(&sums[(size_t)cur * HH + lane], acc);
    if (lane == 0) atomicAdd(&cnts[cur], (float)runlen);
}

// ---------------- classifier + softmax ----------------
__global__ void k_final2(const float* __restrict__ sums, const float* __restrict__ cnts,
                         const float* __restrict__ Wm, const float* __restrict__ bm,
                         float* __restrict__ logits, float* __restrict__ probs,
                         float* __restrict__ graph_emb) {
    int g = blockIdx.x;
    int lane = threadIdx.x;
    float mean = sums[(size_t)g * HH + lane] / fmaxf(cnts[g], 1.0f);
    graph_emb[(size_t)g * HH + lane] = mean;

    __shared__ float semb[HH];
    __shared__ float slog[16];
    semb[lane] = mean;
    __syncthreads();
    if (lane < 10) {
        float acc = bm[lane];
        for (int k = 0; k < HH; ++k) acc = fmaf(semb[k], Wm[k * 10 + lane], acc);
        slog[lane] = acc;
    }
    __syncthreads();
    if (lane < 10) {
        float mx = -1e30f;
        for (int j = 0; j < 10; ++j) mx = fmaxf(mx, slog[j]);
        float den = 0.f;
        for (int j = 0; j < 10; ++j) den += __expf(slog[j] - mx);
        float lg = slog[lane];
        logits[g * 10 + lane] = lg;
        probs[g * 10 + lane] = __expf(lg - mx) / den;
    }
}

// ---------------- launch ----------------

extern "C" void kernel_launch(void* const* d_in, const int* in_sizes, int n_in,
                              void* d_out, int out_size, void* d_ws, size_t ws_size,
                              hipStream_t stream) {
    const float* x     = (const float*)d_in[0];
    const int*   ei    = (const int*)  d_in[1];
    const int*   batch = (const int*)  d_in[2];
    const float* W1 = (const float*)d_in[3];  const float* b1 = (const float*)d_in[4];
    const float* W2 = (const float*)d_in[5];  const float* b2 = (const float*)d_in[6];
    const float* W3 = (const float*)d_in[7];  const float* b3 = (const float*)d_in[8];
    const float* Wm = (const float*)d_in[9];  const float* bm = (const float*)d_in[10];

    const int N = in_sizes[2];
    const int E = in_sizes[1] / 2;
    const int G = (out_size - N * HH) / (2 * 10 + HH);

    const int* row = ei;
    const int* col = ei + E;

    float* out       = (float*)d_out;
    float* logits    = out;
    float* probs     = out + (size_t)G * 10;
    float* node_emb  = out + (size_t)2 * G * 10;
    float* graph_emb = node_emb + (size_t)N * HH;

    char* w = (char*)d_ws;
    auto alloc = [&](size_t bytes) { char* p = w; w += (bytes + 255) & ~(size_t)255; return p; };
    float* dinv    = (float*)alloc((size_t)N * 4);
    int*   cnt     = (int*)  alloc((size_t)N * 4);
    int*   rowptr  = (int*)  alloc((size_t)N * 4);
    int*   head    = (int*)  alloc((size_t)N * 4);
    int*   nxt     = (int*)  alloc((size_t)E * 4);
    int*   cursor  = (int*)  alloc(256);
    float* sums    = (float*)alloc((size_t)G * HH * 4 + (size_t)G * 4);
    float* cnts    = sums + (size_t)G * HH;
    int*   csr     = (int*)  alloc((size_t)E * 4);
    float* bufA    = (float*)alloc((size_t)N * HH * 4);
    float* bufB    = (float*)alloc((size_t)N * HH * 4);

    const int B = 256;
    dim3 blk(B);
    int node_blocks = (N + 3) / 4;
    int gemm_blocks = (N + 63) / 64;
    int nB = (N + B - 1) / B;
    int eB = (E + B - 1) / B;
    int poolN = G * HH + G;
    int pool_blocks = (N + 63) / 64;

    // CSR build: init -> pure link -> fused(walk + layer-1 gemm)
    k_init<<<nB, blk, 0, stream>>>(head, sums, cursor, N, poolN);
    k_link<<<eB, blk, 0, stream>>>(col, E, head, nxt);
    k_walk_gemm<128><<<gemm_blocks, blk, 0, stream>>>(row, head, nxt, cursor, rowptr, cnt,
                                                      dinv, csr, x, W1, bufA, N);

    // layer-1 gather (+fused layer-2 gemm) -> layer-2 gather (+fused layer-3 gemm) -> layer-3 gather
    k_gather_w_gemm<<<node_blocks, blk, 0, stream>>>(bufA, csr, rowptr, cnt, dinv, b1, W2, bufB, N);
    k_gather_gemm<<<node_blocks, blk, 0, stream>>>(bufB, csr, rowptr, cnt, dinv, b2, W3, bufA, N);
    k_gather_final<<<node_blocks, blk, 0, stream>>>(bufA, csr, rowptr, cnt, dinv, b3, node_emb, N);

    // pool + classifier
    k_pool<<<pool_blocks, blk, 0, stream>>>(node_emb, batch, sums, cnts, N);
    k_final2<<<G, dim3(64), 0, stream>>>(sums, cnts, Wm, bm, logits, probs, graph_emb);
}

// Round 15
// 321.797 us; speedup vs baseline: 1.1464x; 1.1464x over previous
//
#include <hip/hip_runtime.h>
#include <math.h>

#define HH 64

// ---------------- init ----------------

__global__ void k_init(int* __restrict__ head, float* __restrict__ sums,
                       int* __restrict__ cursor, int n, int pn) {
    int i = blockIdx.x * blockDim.x + threadIdx.x;
    if (i < n) head[i] = -1;
    if (i < pn) sums[i] = 0.f;
    if (i == 0) *cursor = 0;
}

// ---------------- CSR build: pure linked-list pass (the atomic-scatter floor) ----------------
__global__ void k_link(const int* __restrict__ col, int E,
                       int* __restrict__ head, int* __restrict__ next) {
    int e = blockIdx.x * blockDim.x + threadIdx.x;
    if (e >= E) return;
    int c = col[e];
    int prev = atomicExch(&head[c], e);
    next[e] = prev;
}

// ---------------- fused: list-walk/CSR-alloc + layer-1 GEMM (verified in R13) ----------------
template<int FIN>
__global__ __launch_bounds__(256, 3) void k_walk_gemm(const int* __restrict__ row,
                                                      const int* __restrict__ head,
                                                      const int* __restrict__ next,
                                                      int* __restrict__ cursor,
                                                      int* __restrict__ rowptr,
                                                      int* __restrict__ cnt,
                                                      float* __restrict__ dinv,
                                                      int* __restrict__ csr,
                                                      const float* __restrict__ x,
                                                      const float* __restrict__ W,
                                                      float* __restrict__ lin, int n) {
    constexpr int KC = 32;
    constexpr int XS = 68;
    __shared__ __align__(16) float Ws[FIN][HH];
    __shared__ __align__(16) float xs_t[KC][XS];
    const int tid = threadIdx.x;

    // ---- walk + alloc ----
    {
        int node = blockIdx.x * 256 + tid;
        int lane = tid & 63;
        if (node - tid < n) {
            int len = 0, h = -1;
            if (node < n) {
                h = head[node];
                for (int p = h; p >= 0; p = next[p]) ++len;
                dinv[node] = rsqrtf((float)(len + 1));
            }
            int incl = len;
#pragma unroll
            for (int off = 1; off < 64; off <<= 1) {
                int t = __shfl_up(incl, off, 64);
                if (lane >= off) incl += t;
            }
            int total = __shfl(incl, 63, 64);
            int base = 0;
            if (lane == 0 && total > 0) base = atomicAdd(cursor, total);
            base = __shfl(base, 0, 64);
            int dst = base + incl - len;
            if (node < n) {
                rowptr[node] = dst;
                cnt[node]    = len;
                for (int p = h; p >= 0; p = next[p]) csr[dst++] = row[p];
            }
        }
    }

    // ---- layer-1 gemm (unscaled output) ----
    const int tx = tid & 15;
    const int ty = tid >> 4;
    const int node0 = blockIdx.x * 64;
    if (node0 >= n) return;

    for (int i = tid * 4; i < FIN * HH; i += 1024)
        *(float4*)&Ws[0][i] = *(const float4*)&W[i];

    float acc[4][4] = {};
    const int rr0 = tid >> 3;
    const int cc  = (tid & 7) * 4;

    for (int kc = 0; kc < FIN; kc += KC) {
        __syncthreads();
        for (int rr = rr0; rr < 64; rr += 32) {
            float4 v = make_float4(0.f, 0.f, 0.f, 0.f);
            if (node0 + rr < n) v = *(const float4*)&x[(size_t)(node0 + rr) * FIN + kc + cc];
            xs_t[cc + 0][rr] = v.x;
            xs_t[cc + 1][rr] = v.y;
            xs_t[cc + 2][rr] = v.z;
            xs_t[cc + 3][rr] = v.w;
        }
        __syncthreads();
#pragma unroll 4
        for (int k = 0; k < KC; ++k) {
            float4 a4 = *(const float4*)&xs_t[k][ty * 4];
            float4 b4 = *(const float4*)&Ws[kc + k][tx * 4];
            acc[0][0] = fmaf(a4.x, b4.x, acc[0][0]);
            acc[0][1] = fmaf(a4.x, b4.y, acc[0][1]);
            acc[0][2] = fmaf(a4.x, b4.z, acc[0][2]);
            acc[0][3] = fmaf(a4.x, b4.w, acc[0][3]);
            acc[1][0] = fmaf(a4.y, b4.x, acc[1][0]);
            acc[1][1] = fmaf(a4.y, b4.y, acc[1][1]);
            acc[1][2] = fmaf(a4.y, b4.z, acc[1][2]);
            acc[1][3] = fmaf(a4.y, b4.w, acc[1][3]);
            acc[2][0] = fmaf(a4.z, b4.x, acc[2][0]);
            acc[2][1] = fmaf(a4.z, b4.y, acc[2][1]);
            acc[2][2] = fmaf(a4.z, b4.z, acc[2][2]);
            acc[2][3] = fmaf(a4.z, b4.w, acc[2][3]);
            acc[3][0] = fmaf(a4.w, b4.x, acc[3][0]);
            acc[3][1] = fmaf(a4.w, b4.y, acc[3][1]);
            acc[3][2] = fmaf(a4.w, b4.z, acc[3][2]);
            acc[3][3] = fmaf(a4.w, b4.w, acc[3][3]);
        }
    }

#pragma unroll
    for (int i = 0; i < 4; ++i) {
        int node = node0 + ty * 4 + i;
        if (node < n) *(float4*)&lin[(size_t)node * HH + tx * 4] = *(float4*)acc[i];
    }
}

// ---------------- dense transform (layers 2-3): pre-scaled by dinv ----------------
template<int FIN>
__global__ __launch_bounds__(256, 4) void k_gemm2(const float* __restrict__ x,
                                                  const float* __restrict__ W,
                                                  const float* __restrict__ dinv,
                                                  float* __restrict__ linS, int n) {
    constexpr int KC = 32;
    constexpr int XS = 68;
    __shared__ __align__(16) float Ws[FIN][HH];
    __shared__ __align__(16) float xs_t[KC][XS];
    const int tid = threadIdx.x;
    const int tx = tid & 15;
    const int ty = tid >> 4;
    const int node0 = blockIdx.x * 64;

    for (int i = tid * 4; i < FIN * HH; i += 1024)
        *(float4*)&Ws[0][i] = *(const float4*)&W[i];

    float acc[4][4] = {};
    const int rr0 = tid >> 3;
    const int cc  = (tid & 7) * 4;

    for (int kc = 0; kc < FIN; kc += KC) {
        __syncthreads();
        for (int rr = rr0; rr < 64; rr += 32) {
            float4 v = make_float4(0.f, 0.f, 0.f, 0.f);
            if (node0 + rr < n) v = *(const float4*)&x[(size_t)(node0 + rr) * FIN + kc + cc];
            xs_t[cc + 0][rr] = v.x;
            xs_t[cc + 1][rr] = v.y;
            xs_t[cc + 2][rr] = v.z;
            xs_t[cc + 3][rr] = v.w;
        }
        __syncthreads();
#pragma unroll 4
        for (int k = 0; k < KC; ++k) {
            float4 a4 = *(const float4*)&xs_t[k][ty * 4];
            float4 b4 = *(const float4*)&Ws[kc + k][tx * 4];
            acc[0][0] = fmaf(a4.x, b4.x, acc[0][0]);
            acc[0][1] = fmaf(a4.x, b4.y, acc[0][1]);
            acc[0][2] = fmaf(a4.x, b4.z, acc[0][2]);
            acc[0][3] = fmaf(a4.x, b4.w, acc[0][3]);
            acc[1][0] = fmaf(a4.y, b4.x, acc[1][0]);
            acc[1][1] = fmaf(a4.y, b4.y, acc[1][1]);
            acc[1][2] = fmaf(a4.y, b4.z, acc[1][2]);
            acc[1][3] = fmaf(a4.y, b4.w, acc[1][3]);
            acc[2][0] = fmaf(a4.z, b4.x, acc[2][0]);
            acc[2][1] = fmaf(a4.z, b4.y, acc[2][1]);
            acc[2][2] = fmaf(a4.z, b4.z, acc[2][2]);
            acc[2][3] = fmaf(a4.z, b4.w, acc[2][3]);
            acc[3][0] = fmaf(a4.w, b4.x, acc[3][0]);
            acc[3][1] = fmaf(a4.w, b4.y, acc[3][1]);
            acc[3][2] = fmaf(a4.w, b4.z, acc[3][2]);
            acc[3][3] = fmaf(a4.w, b4.w, acc[3][3]);
        }
    }

#pragma unroll
    for (int i = 0; i < 4; ++i) {
        int node = node0 + ty * 4 + i;
        if (node < n) {
            float d = dinv[node];
            float4 o = make_float4(acc[i][0] * d, acc[i][1] * d, acc[i][2] * d, acc[i][3] * d);
            *(float4*)&linS[(size_t)node * HH + tx * 4] = o;
        }
    }
}

// ---------------- layer-1 gather: lin unscaled, weight = dinv[src] per edge (R12-verified) ----------------
__global__ void k_gather_w(const float* __restrict__ lin, const int* __restrict__ csr,
                           const int* __restrict__ rowptr, const int* __restrict__ cnt,
                           const float* __restrict__ dinv, const float* __restrict__ b,
                           float* __restrict__ hout, int n) {
    int node = blockIdx.x * (blockDim.x >> 6) + (threadIdx.x >> 6);
    int lane = threadIdx.x & 63;
    if (node >= n) return;
    int start = rowptr[node];
    int end = start + cnt[node];
    float di = dinv[node];
    float acc0 = di * lin[(size_t)node * HH + lane];   // self: dinv[c]*lin[c]
    float acc1 = 0.f, acc2 = 0.f, acc3 = 0.f;
    for (int base = start; base < end; base += 64) {
        int m = end - base; if (m > 64) m = 64;
        int   sv = (base + lane < end) ? csr[base + lane] : 0;
        float wv = (base + lane < end) ? dinv[sv] : 0.f;
        int j = 0;
        for (; j + 3 < m; j += 4) {
            int s0 = __shfl(sv, j, 64);     float w0 = __shfl(wv, j, 64);
            int s1 = __shfl(sv, j + 1, 64); float w1 = __shfl(wv, j + 1, 64);
            int s2 = __shfl(sv, j + 2, 64); float w2 = __shfl(wv, j + 2, 64);
            int s3 = __shfl(sv, j + 3, 64); float w3 = __shfl(wv, j + 3, 64);
            float v0 = lin[(size_t)s0 * HH + lane];
            float v1 = lin[(size_t)s1 * HH + lane];
            float v2 = lin[(size_t)s2 * HH + lane];
            float v3 = lin[(size_t)s3 * HH + lane];
            acc0 = fmaf(w0, v0, acc0);
            acc1 = fmaf(w1, v1, acc1);
            acc2 = fmaf(w2, v2, acc2);
            acc3 = fmaf(w3, v3, acc3);
        }
        for (; j < m; ++j) {
            int s0 = __shfl(sv, j, 64); float w0 = __shfl(wv, j, 64);
            acc0 = fmaf(w0, lin[(size_t)s0 * HH + lane], acc0);
        }
    }
    float v = di * ((acc0 + acc1) + (acc2 + acc3)) + b[lane];
    float ss = v * v;
#pragma unroll
    for (int off = 1; off < 64; off <<= 1) ss += __shfl_xor(ss, off, 64);
    v = v / fmaxf(sqrtf(ss), 1e-12f);
    hout[(size_t)node * HH + lane] = fmaxf(v, 0.f);
}

// ---------------- layers 2-3 gather: linS pre-scaled (R10/R11-verified) ----------------
__global__ void k_gather(const float* __restrict__ linS, const int* __restrict__ csr,
                         const int* __restrict__ rowptr, const int* __restrict__ cnt,
                         const float* __restrict__ dinv, const float* __restrict__ b,
                         float* __restrict__ hout, int n) {
    int node = blockIdx.x * (blockDim.x >> 6) + (threadIdx.x >> 6);
    int lane = threadIdx.x & 63;
    if (node >= n) return;
    int start = rowptr[node];
    int end = start + cnt[node];
    float di = dinv[node];
    float acc0 = linS[(size_t)node * HH + lane];   // self term (carries one dinv[c])
    float acc1 = 0.f, acc2 = 0.f, acc3 = 0.f;
    for (int base = start; base < end; base += 64) {
        int m = end - base; if (m > 64) m = 64;
        int sv = (base + lane < end) ? csr[base + lane] : 0;
        int j = 0;
        for (; j + 7 < m; j += 8) {
            int s0 = __shfl(sv, j, 64);
            int s1 = __shfl(sv, j + 1, 64);
            int s2 = __shfl(sv, j + 2, 64);
            int s3 = __shfl(sv, j + 3, 64);
            int s4 = __shfl(sv, j + 4, 64);
            int s5 = __shfl(sv, j + 5, 64);
            int s6 = __shfl(sv, j + 6, 64);
            int s7 = __shfl(sv, j + 7, 64);
            float v0 = linS[(size_t)s0 * HH + lane];
            float v1 = linS[(size_t)s1 * HH + lane];
            float v2 = linS[(size_t)s2 * HH + lane];
            float v3 = linS[(size_t)s3 * HH + lane];
            float v4 = linS[(size_t)s4 * HH + lane];
            float v5 = linS[(size_t)s5 * HH + lane];
            float v6 = linS[(size_t)s6 * HH + lane];
            float v7 = linS[(size_t)s7 * HH + lane];
            acc0 += v0; acc1 += v1; acc2 += v2; acc3 += v3;
            acc0 += v4; acc1 += v5; acc2 += v6; acc3 += v7;
        }
        for (; j < m; ++j) {
            int s0 = __shfl(sv, j, 64);
            acc0 += linS[(size_t)s0 * HH + lane];
        }
    }
    float v = di * ((acc0 + acc1) + (acc2 + acc3)) + b[lane];
    float ss = v * v;
#pragma unroll
    for (int off = 1; off < 64; off <<= 1) ss += __shfl_xor(ss, off, 64);
    v = v / fmaxf(sqrtf(ss), 1e-12f);
    hout[(size_t)node * HH + lane] = fmaxf(v, 0.f);
}

// ---------------- pooling ----------------
__global__ __launch_bounds__(256) void k_pool(const float* __restrict__ node_emb,
                                              const int* __restrict__ batch,
                                              float* __restrict__ sums,
                                              float* __restrict__ cnts, int n) {
    const int NPW = 16;
    int wave = blockIdx.x * 4 + (threadIdx.x >> 6);
    int lane = threadIdx.x & 63;
    int start = wave * NPW;
    if (start >= n) return;
    int end = start + NPW; if (end > n) end = n;
    int cur = batch[start];
    float acc = 0.f;
    int runlen = 0;
    for (int node = start; node < end; ++node) {
        int g = batch[node];
        if (g != cur) {
            atomicAdd(&sums[(size_t)cur * HH + lane], acc);
            if (lane == 0) atomicAdd(&cnts[cur], (float)runlen);
            acc = 0.f; runlen = 0; cur = g;
        }
        acc += node_emb[(size_t)node * HH + lane];
        ++runlen;
    }
    atomicAdd(&sums[(size_t)cur * HH + lane], acc);
    if (lane == 0) atomicAdd(&cnts[cur], (float)runlen);
}

// ---------------- classifier + softmax ----------------
__global__ void k_final2(const float* __restrict__ sums, const float* __restrict__ cnts,
                         const float* __restrict__ Wm, const float* __restrict__ bm,
                         float* __restrict__ logits, float* __restrict__ probs,
                         float* __restrict__ graph_emb) {
    int g = blockIdx.x;
    int lane = threadIdx.x;
    float mean = sums[(size_t)g * HH + lane] / fmaxf(cnts[g], 1.0f);
    graph_emb[(size_t)g * HH + lane] = mean;

    __shared__ float semb[HH];
    __shared__ float slog[16];
    semb[lane] = mean;
    __syncthreads();
    if (lane < 10) {
        float acc = bm[lane];
        for (int k = 0; k < HH; ++k) acc = fmaf(semb[k], Wm[k * 10 + lane], acc);
        slog[lane] = acc;
    }
    __syncthreads();
    if (lane < 10) {
        float mx = -1e30f;
        for (int j = 0; j < 10; ++j) mx = fmaxf(mx, slog[j]);
        float den = 0.f;
        for (int j = 0; j < 10; ++j) den += __expf(slog[j] - mx);
        float lg = slog[lane];
        logits[g * 10 + lane] = lg;
        probs[g * 10 + lane] = __expf(lg - mx) / den;
    }
}

// ---------------- launch ----------------

extern "C" void kernel_launch(void* const* d_in, const int* in_sizes, int n_in,
                              void* d_out, int out_size, void* d_ws, size_t ws_size,
                              hipStream_t stream) {
    const float* x     = (const float*)d_in[0];
    const int*   ei    = (const int*)  d_in[1];
    const int*   batch = (const int*)  d_in[2];
    const float* W1 = (const float*)d_in[3];  const float* b1 = (const float*)d_in[4];
    const float* W2 = (const float*)d_in[5];  const float* b2 = (const float*)d_in[6];
    const float* W3 = (const float*)d_in[7];  const float* b3 = (const float*)d_in[8];
    const float* Wm = (const float*)d_in[9];  const float* bm = (const float*)d_in[10];

    const int N = in_sizes[2];
    const int E = in_sizes[1] / 2;
    const int G = (out_size - N * HH) / (2 * 10 + HH);

    const int* row = ei;
    const int* col = ei + E;

    float* out       = (float*)d_out;
    float* logits    = out;
    float* probs     = out + (size_t)G * 10;
    float* node_emb  = out + (size_t)2 * G * 10;
    float* graph_emb = node_emb + (size_t)N * HH;

    char* w = (char*)d_ws;
    auto alloc = [&](size_t bytes) { char* p = w; w += (bytes + 255) & ~(size_t)255; return p; };
    float* dinv    = (float*)alloc((size_t)N * 4);
    int*   cnt     = (int*)  alloc((size_t)N * 4);
    int*   rowptr  = (int*)  alloc((size_t)N * 4);
    int*   head    = (int*)  alloc((size_t)N * 4);
    int*   nxt     = (int*)  alloc((size_t)E * 4);
    int*   cursor  = (int*)  alloc(256);
    float* sums    = (float*)alloc((size_t)G * HH * 4 + (size_t)G * 4);
    float* cnts    = sums + (size_t)G * HH;
    int*   csr     = (int*)  alloc((size_t)E * 4);
    float* bufA    = (float*)alloc((size_t)N * HH * 4);
    float* bufB    = (float*)alloc((size_t)N * HH * 4);

    const int B = 256;
    dim3 blk(B);
    int node_blocks = (N + 3) / 4;
    int gemm_blocks = (N + 63) / 64;
    int nB = (N + B - 1) / B;
    int eB = (E + B - 1) / B;
    int poolN = G * HH + G;
    int pool_blocks = (N + 63) / 64;

    // CSR build: init -> pure link -> fused(walk + layer-1 gemm, unscaled lin -> bufA)
    k_init<<<nB, blk, 0, stream>>>(head, sums, cursor, N, poolN);
    k_link<<<eB, blk, 0, stream>>>(col, E, head, nxt);
    k_walk_gemm<128><<<gemm_blocks, blk, 0, stream>>>(row, head, nxt, cursor, rowptr, cnt,
                                                      dinv, csr, x, W1, bufA, N);

    // layer 1: weighted gather (bufA -> bufB = h1)
    k_gather_w<<<node_blocks, blk, 0, stream>>>(bufA, csr, rowptr, cnt, dinv, b1, bufB, N);
    // layer 2: gemm (bufB -> bufA = linS) + gather (bufA -> bufB = h2)
    k_gemm2<64><<<gemm_blocks, blk, 0, stream>>>(bufB, W2, dinv, bufA, N);
    k_gather<<<node_blocks, blk, 0, stream>>>(bufA, csr, rowptr, cnt, dinv, b2, bufB, N);
    // layer 3: gemm (bufB -> bufA = linS) + gather (bufA -> node_emb)
    k_gemm2<64><<<gemm_blocks, blk, 0, stream>>>(bufB, W3, dinv, bufA, N);
    k_gather<<<node_blocks, blk, 0, stream>>>(bufA, csr, rowptr, cnt, dinv, b3, node_emb, N);

    // pool + classifier
    k_pool<<<pool_blocks, blk, 0, stream>>>(node_emb, batch, sums, cnts, N);
    k_final2<<<G, dim3(64), 0, stream>>>(sums, cnts, Wm, bm, logits, probs, graph_emb);
}